// Round 1
// baseline (24583.107 us; speedup 1.0000x reference)
//
#include <hip/hip_runtime.h>
#include <cstddef>
#include <cstdint>

namespace {

constexpr int B = 256, S = 128, H = 512;
constexpr int SS = S * S;

// ---------------------------------------------------------------------------
// init: h <- h0, c <- c0, mask <- 1
// ---------------------------------------------------------------------------
__global__ __launch_bounds__(256) void init_kernel(float* __restrict__ h,
                                                   float* __restrict__ c,
                                                   float* __restrict__ mask,
                                                   const float* __restrict__ h0,
                                                   const float* __restrict__ c0) {
  int tid = blockIdx.x * 256 + threadIdx.x;
  if (tid < B * H) {
    h[tid] = h0[tid];
    c[tid] = c0[tid];
  }
  if (tid < B * S) mask[tid] = 1.0f;
}

// ---------------------------------------------------------------------------
// Generic fp32 GEMM: C = epi( A1@B1 [+ A2@B2] [+ bias1] [+ bias2] )
// A row-major (M x K), B row-major (K x N, ldb == N), C row-major (M x N).
// If sel != nullptr, part-2 rows are gathered: row r of A2 is
//   A2 + (r*selStride + sel[r]) * K2   (pointer-net input gather).
// EPI: 0 = identity, 1 = tanh.
// Requires M % BM == 0, N % BN == 0, K % KT == 0, KT % 4 == 0, BN % 4 == 0.
// ---------------------------------------------------------------------------
template <int BM, int BN, int TM, int TN, int KT, int EPI>
__global__ __launch_bounds__((BM / TM) * (BN / TN)) void gemm_k(
    const float* __restrict__ A1, const float* __restrict__ B1, int K1,
    const float* __restrict__ A2, const float* __restrict__ B2, int K2,
    const int* __restrict__ sel, int selStride,
    const float* __restrict__ bias1, const float* __restrict__ bias2,
    float* __restrict__ C, int M, int N) {
  constexpr int THREADS = (BM / TM) * (BN / TN);
  const int tid = threadIdx.x;
  const int n0 = blockIdx.x * BN;
  const int m0 = blockIdx.y * BM;

  __shared__ float As[KT][BM + 4];  // +4 pad keeps 16B alignment & breaks bank conflicts
  __shared__ float Bs[KT][BN];

  float acc[TM][TN];
#pragma unroll
  for (int i = 0; i < TM; ++i)
#pragma unroll
    for (int j = 0; j < TN; ++j) acc[i][j] = 0.f;

  const int tn = tid % (BN / TN);
  const int tm = tid / (BN / TN);

  for (int part = 0; part < 2; ++part) {
    const float* A = part ? A2 : A1;
    const float* Bp = part ? B2 : B1;
    const int K = part ? K2 : K1;
    if (A == nullptr || K == 0) continue;
    const bool gather = (part == 1) && (sel != nullptr);

    for (int kk = 0; kk < K; kk += KT) {
      // --- stage A tile (transposed into LDS) ---
      for (int idx = tid; idx < BM * (KT / 4); idx += THREADS) {
        int row = idx / (KT / 4), kq = idx % (KT / 4);
        const float* ar;
        if (gather) {
          int gr = m0 + row;
          ar = A + ((size_t)gr * selStride + sel[gr]) * (size_t)K;
        } else {
          ar = A + (size_t)(m0 + row) * (size_t)K;
        }
        float4 a4 = *reinterpret_cast<const float4*>(ar + kk + kq * 4);
        As[kq * 4 + 0][row] = a4.x;
        As[kq * 4 + 1][row] = a4.y;
        As[kq * 4 + 2][row] = a4.z;
        As[kq * 4 + 3][row] = a4.w;
      }
      // --- stage B tile ---
      for (int idx = tid; idx < KT * (BN / 4); idx += THREADS) {
        int k = idx / (BN / 4), n4 = idx % (BN / 4);
        *reinterpret_cast<float4*>(&Bs[k][n4 * 4]) =
            *reinterpret_cast<const float4*>(Bp + (size_t)(kk + k) * N + n0 + n4 * 4);
      }
      __syncthreads();
#pragma unroll
      for (int k = 0; k < KT; ++k) {
        float a[TM], bb[TN];
#pragma unroll
        for (int i = 0; i < TM; ++i) a[i] = As[k][tm * TM + i];
#pragma unroll
        for (int j = 0; j < TN; ++j) bb[j] = Bs[k][tn * TN + j];
#pragma unroll
        for (int i = 0; i < TM; ++i)
#pragma unroll
          for (int j = 0; j < TN; ++j) acc[i][j] = fmaf(a[i], bb[j], acc[i][j]);
      }
      __syncthreads();
    }
  }

#pragma unroll
  for (int i = 0; i < TM; ++i) {
    int row = m0 + tm * TM + i;
#pragma unroll
    for (int j = 0; j < TN; ++j) {
      int col = n0 + tn * TN + j;
      float x = acc[i][j];
      if (bias1) x += bias1[col];
      if (bias2) x += bias2[col];
      if (EPI == 1) x = tanhf(x);
      C[(size_t)row * N + col] = x;
    }
  }
}

// ---------------------------------------------------------------------------
// LSTM cell pointwise: gates (B x 4H) -> c (in-place), h_i
// split order: i, f, g, o ; sigmoid applied to ALL four (incl. cell gate g).
// ---------------------------------------------------------------------------
__device__ __forceinline__ float sigmf(float x) { return 1.f / (1.f + expf(-x)); }

__global__ __launch_bounds__(256) void cell_kernel(const float* __restrict__ gates,
                                                   float* __restrict__ c,
                                                   float* __restrict__ h_i) {
  int tid = blockIdx.x * 256 + threadIdx.x;
  if (tid >= B * H) return;
  int b = tid >> 9;          // /512
  int j = tid & (H - 1);     // %512
  size_t base = (size_t)b * (4 * H) + j;
  float gi = sigmf(gates[base]);
  float gf = sigmf(gates[base + H]);
  float gg = sigmf(gates[base + 2 * H]);
  float go = sigmf(gates[base + 3 * H]);
  float cn = gf * c[tid] + gi * gg;
  c[tid] = cn;
  h_i[tid] = go * tanhf(cn);
}

// ---------------------------------------------------------------------------
// Attention: one block per batch row b (256 threads).
// scores[s] = sum_h v[h] * tanh(ctx_proj[b,s,h] + q[b,h]);  mask -> -1e9
// alpha = softmax(scores); write alpha row into outputs[b, t, :]
// idx = argmax(alpha * mask) (first-index tiebreak, numpy semantics)
// write pointer, update mask, sel; att[b,:] = sum_s alpha[s]*context[b,s,:]
// ---------------------------------------------------------------------------
__global__ __launch_bounds__(256) void attn_kernel(
    const float* __restrict__ ctx_proj, const float* __restrict__ context,
    const float* __restrict__ q, const float* __restrict__ v,
    float* __restrict__ mask, float* __restrict__ out /* d_out base */,
    float* __restrict__ att, int* __restrict__ sel, int t) {
  const int b = blockIdx.x;
  const int tid = threadIdx.x;
  __shared__ float qs[H], vs[H], sc[S], al[S];
  __shared__ float redm[4], reds[4], redv[4];
  __shared__ int redi[4];

  qs[tid] = q[(size_t)b * H + tid];
  qs[tid + 256] = q[(size_t)b * H + 256 + tid];
  vs[tid] = v[tid];
  vs[tid + 256] = v[tid + 256];
  __syncthreads();

  // --- scores: 2 threads per s, 256 h each ---
  const int s = tid >> 1;
  const int half = tid & 1;
  const int hb = half * 256;
  const float* cp = ctx_proj + ((size_t)b * S + s) * H + hb;
  float p = 0.f;
#pragma unroll 4
  for (int i = 0; i < 256; i += 4) {
    float4 c4 = *reinterpret_cast<const float4*>(cp + i);
    p += vs[hb + i + 0] * tanhf(c4.x + qs[hb + i + 0]);
    p += vs[hb + i + 1] * tanhf(c4.y + qs[hb + i + 1]);
    p += vs[hb + i + 2] * tanhf(c4.z + qs[hb + i + 2]);
    p += vs[hb + i + 3] * tanhf(c4.w + qs[hb + i + 3]);
  }
  p += __shfl_xor(p, 1);
  if (!half) sc[s] = (mask[(size_t)b * S + s] == 0.f) ? -1e9f : p;
  __syncthreads();

  // --- softmax over 128 scores ---
  float x = (tid < S) ? sc[tid] : -3.0e38f;
  float wm = x;
  for (int o = 1; o < 64; o <<= 1) wm = fmaxf(wm, __shfl_xor(wm, o));
  if ((tid & 63) == 0) redm[tid >> 6] = wm;
  __syncthreads();
  float m = fmaxf(fmaxf(redm[0], redm[1]), fmaxf(redm[2], redm[3]));
  float e = (tid < S) ? expf(sc[tid] - m) : 0.f;
  float wsum = e;
  for (int o = 1; o < 64; o <<= 1) wsum += __shfl_xor(wsum, o);
  if ((tid & 63) == 0) reds[tid >> 6] = wsum;
  __syncthreads();
  float sum = reds[0] + reds[1] + reds[2] + reds[3];
  float a = e / sum;
  if (tid < S) {
    al[tid] = a;
    out[((size_t)b * S + t) * S + tid] = a;  // outputs[b, t, s]
  }
  __syncthreads();

  // --- argmax(alpha * mask), first-index tiebreak ---
  float mv = (tid < S) ? al[tid] * mask[(size_t)b * S + tid] : -1.f;
  int mi = tid & (S - 1);
  for (int o = 1; o < 64; o <<= 1) {
    float ov = __shfl_xor(mv, o);
    int oi = __shfl_xor(mi, o);
    if (ov > mv || (ov == mv && oi < mi)) { mv = ov; mi = oi; }
  }
  if ((tid & 63) == 0) { redv[tid >> 6] = mv; redi[tid >> 6] = mi; }
  __syncthreads();
  if (tid == 0) {
    float bv = redv[0];
    int bI = redi[0];
    for (int w = 1; w < 4; ++w) {
      if (redv[w] > bv || (redv[w] == bv && redi[w] < bI)) { bv = redv[w]; bI = redi[w]; }
    }
    out[(size_t)B * SS + (size_t)b * S + t] = (float)bI;  // pointers[b, t]
    mask[(size_t)b * S + bI] = 0.f;
    sel[b] = bI;
  }
  __syncthreads();

  // --- att[b, :] = sum_s alpha[s] * context[b, s, :]  (2 cols/thread) ---
  const int c0 = tid * 2;
  float2 acc2 = {0.f, 0.f};
  const float* cb = context + (size_t)b * S * H + c0;
  for (int s2 = 0; s2 < S; ++s2) {
    float2 cx = *reinterpret_cast<const float2*>(cb + (size_t)s2 * H);
    float aa = al[s2];
    acc2.x += aa * cx.x;
    acc2.y += aa * cx.y;
  }
  *reinterpret_cast<float2*>(att + (size_t)b * H + c0) = acc2;
}

}  // namespace

// ---------------------------------------------------------------------------
extern "C" void kernel_launch(void* const* d_in, const int* in_sizes, int n_in,
                              void* d_out, int out_size, void* d_ws, size_t ws_size,
                              hipStream_t stream) {
  const float* emb  = (const float*)d_in[0];   // (B,S,H)
  const float* dec  = (const float*)d_in[1];   // (B,H)
  const float* h0   = (const float*)d_in[2];   // (B,H)
  const float* c0   = (const float*)d_in[3];   // (B,H)
  const float* ctx  = (const float*)d_in[4];   // (B,S,H)
  const float* Wi   = (const float*)d_in[5];   // (H,4H)
  const float* bi   = (const float*)d_in[6];   // (4H)
  const float* Wh   = (const float*)d_in[7];   // (H,4H)
  const float* bh   = (const float*)d_in[8];   // (4H)
  const float* Wctx = (const float*)d_in[9];   // (H,H)
  const float* Wha  = (const float*)d_in[10];  // (H,H)
  const float* v    = (const float*)d_in[11];  // (H)
  const float* Wout = (const float*)d_in[12];  // (2H,H)
  const float* bout = (const float*)d_in[13];  // (H)
  float* out = (float*)d_out;

  // workspace layout (floats); total ~17.99M floats ~= 72 MB
  float* ws = (float*)d_ws;
  float* ctxp  = ws;                       // B*S*H = 16,777,216
  float* gates = ctxp + (size_t)B * S * H; // B*4H  =    524,288
  float* g_h   = gates + (size_t)B * 4 * H;
  float* g_c   = g_h + (size_t)B * H;
  float* g_hi  = g_c + (size_t)B * H;
  float* g_q   = g_hi + (size_t)B * H;
  float* g_att = g_q + (size_t)B * H;
  float* g_msk = g_att + (size_t)B * H;    // B*S
  int*   g_sel = (int*)(g_msk + (size_t)B * S);

  // init h, c, mask
  init_kernel<<<(B * H + 255) / 256, 256, 0, stream>>>(g_h, g_c, g_msk, h0, c0);

  // ctx_proj = context @ Wctx  (32768 x 512, K=512)
  gemm_k<128, 64, 8, 4, 16, 0><<<dim3(H / 64, (B * S) / 128), 256, 0, stream>>>(
      ctx, Wctx, H, nullptr, nullptr, 0, nullptr, 0, nullptr, nullptr, ctxp, B * S, H);

  for (int t = 0; t < S; ++t) {
    const float* xA = (t == 0) ? dec : emb;
    const int* selp = (t == 0) ? nullptr : g_sel;
    // gates = h @ Wh + gather(x) @ Wi + bi + bh   (256 x 2048)
    gemm_k<32, 64, 2, 4, 16, 0><<<dim3((4 * H) / 64, B / 32), 256, 0, stream>>>(
        g_h, Wh, H, xA, Wi, H, selp, S, bi, bh, gates, B, 4 * H);
    // LSTM cell
    cell_kernel<<<(B * H + 255) / 256, 256, 0, stream>>>(gates, g_c, g_hi);
    // q = h_i @ Wha  (256 x 512)
    gemm_k<32, 32, 2, 2, 16, 0><<<dim3(H / 32, B / 32), 256, 0, stream>>>(
        g_hi, Wha, H, nullptr, nullptr, 0, nullptr, 0, nullptr, nullptr, g_q, B, H);
    // attention + softmax + argmax + mask update + att
    attn_kernel<<<B, 256, 0, stream>>>(ctxp, ctx, g_q, v, g_msk, out, g_att, g_sel, t);
    // h = tanh([att, h_i] @ Wout + bout)  (virtual concat: two K=512 parts)
    gemm_k<32, 32, 2, 2, 16, 1><<<dim3(H / 32, B / 32), 256, 0, stream>>>(
        g_att, Wout, H, g_hi, Wout + (size_t)H * H, H, nullptr, 0, bout, nullptr,
        g_h, B, H);
  }
}